// Round 16
// baseline (633.030 us; speedup 1.0000x reference)
//
#include <hip/hip_runtime.h>
#include <hip/hip_bf16.h>
#include <stdint.h>

#define L_ 2
#define N_ 100000
#define D_ 512
#define B_ 256
#define C_ 10
#define K_ 75
#define NCALI_ 750
#define CAP_ 2048       // per-row candidate capacity in k_select (expect ~360 at z>2.7)
#define RCAP_ 1024      // rescore-set capacity (expect ~95)
#define TAUZ 2.7f       // pre-threshold in z units (true 75th at z~3.17, min ~3.0)
#define TAUC_ (TAUZ / 22.627416997969522f)
#define MARGIN 0.06f    // >> 5-sigma bf16 dot error (~0.008)
#define NG_ 3125        // 32-row groups per layer (3125*32 = 100000 exactly)
#define GTOT_ (L_ * NG_)
#define SLOTS_ 2        // slots per (query, group) cell; overflow list catches rest
#define OVF_CAP 65536

typedef unsigned short u16;
typedef __attribute__((ext_vector_type(8))) short short8;
typedef __attribute__((ext_vector_type(4))) float f32x4;

// lgkm-only raw barrier: LDS visibility; NO vmcnt — all vm waits are precise reg-deps
#define BAR_LG() asm volatile("s_waitcnt lgkmcnt(0)\n\ts_barrier" ::: "memory")
#define SCHED_PIN() __builtin_amdgcn_sched_barrier(0)

// pack two floats into two rounded bf16s (lo in low 16 bits)
__device__ __forceinline__ unsigned pk_bf16(float lo, float hi) {
  unsigned a = __float_as_uint(lo) + 0x8000u;
  unsigned b = __float_as_uint(hi) + 0x8000u;
  return (a >> 16) | (b & 0xffff0000u);
}

// ---- zero the slot slab + overflow counter (every call: replay determinism) ----
__global__ __launch_bounds__(256) void k_zero(uint4* __restrict__ p, long n16,
                                              unsigned* __restrict__ ovfCnt) {
  long i = (long)blockIdx.x * 256 + threadIdx.x;
  const long stride = (long)gridDim.x * 256;
  const uint4 z = {0u, 0u, 0u, 0u};
  for (; i < n16; i += stride) p[i] = z;
  if (blockIdx.x == 0 && threadIdx.x == 0) *ovfCnt = 0u;
}

// ---- query -> bf16 (linear), query norms, zero class counts ----
__global__ __launch_bounds__(64) void k_qprep(const float* __restrict__ qf,
                                              u16* __restrict__ qb,
                                              float* __restrict__ qn,
                                              int* __restrict__ counts) {
  const int row  = blockIdx.x;      // 0..511 (l*256+b)
  const int lane = threadIdx.x;     // 0..63
  const float* src = qf + (size_t)row * D_ + lane * 8;
  float4 a = *(const float4*)(src);
  float4 b = *(const float4*)(src + 4);
  uint4 o;
  o.x = pk_bf16(a.x, a.y); o.y = pk_bf16(a.z, a.w);
  o.z = pk_bf16(b.x, b.y); o.w = pk_bf16(b.z, b.w);
  *(uint4*)(qb + (size_t)row * D_ + lane * 8) = o;
  float ss = a.x*a.x + a.y*a.y + a.z*a.z + a.w*a.w
           + b.x*b.x + b.y*b.y + b.z*b.z + b.w*b.w;
#pragma unroll
  for (int off = 32; off; off >>= 1) ss += __shfl_xor(ss, off);
  if (lane == 0) qn[row] = sqrtf(ss);
  if (row == 0)
    for (int i = lane; i < B_ * C_; i += 64) counts[i] = 0;
}

// ---- fused GEMM: full-row streaming groups ----
// Group = 32 train rows x full D=512, read as CONTIGUOUS 512B spans (DRAM-row friendly).
// BM=256 queries, K-loop inside group (8 kt x BK=64). A (L2-hot) streamed per kt via
// As dbuf; B converted fp32->bf16 in regs (2 batches of 16 rows) into Bs dbuf.
// All barriers lgkm-only; every vm wait is a precise reg-dep on the oldest set.
__global__ __launch_bounds__(512, 1) void k_gemm(const float* __restrict__ tf,
                                                 const u16* __restrict__ qb,
                                                 const float* __restrict__ qn,
                                                 uint2* __restrict__ slots,
                                                 uint2* __restrict__ ovf,
                                                 unsigned* __restrict__ ovfCnt) {
  __shared__ __align__(16) u16 As[2][256 * 64];   // 2x32 KB, XOR-swizzled (8 gran/row)
  __shared__ __align__(16) u16 Bs[2][32 * 512];   // 2x32 KB, full-D rows, 64 gran/row
  __shared__ float rnS[2][32];
  __shared__ float tauS[B_];
  __shared__ int   lcnt[B_];
  const int tid  = threadIdx.x, lane = tid & 63, wave = tid >> 6;
  const int wm   = wave >> 1, wn = wave & 1;      // 4 m-slices x 2 n-halves
  const int kg   = lane >> 4, rl = lane & 15;
  const int ar   = tid >> 3, ag = tid & 7;        // A-stage: rows j*64+ar, granule ag
  const int brow = tid >> 5, bc = tid & 31;       // B-stage: row-in-batch, 32 thr/row

  if (tid < B_) { tauS[tid] = qn[tid] * TAUC_; lcnt[tid] = 0; }

  f32x4 acc[4];
  const f32x4 vz = {0.f, 0.f, 0.f, 0.f};
#pragma unroll
  for (int i = 0; i < 4; ++i) acc[i] = vz;

  uint4  va[4];
  float4 vb0[4], vb1[4];

#define LOAD_A(QB, KT)                                                          \
  _Pragma("unroll") for (int _j = 0; _j < 4; ++_j) {                            \
    const int _r = _j * 64 + ar;                                                \
    va[_j] = *(const uint4*)((QB) + (size_t)_r * D_ + (KT) * 64 + ag * 8);      \
  }
#define STORE_A(P)                                                              \
  _Pragma("unroll") for (int _j = 0; _j < 4; ++_j) {                            \
    const int _r = _j * 64 + ar;                                                \
    *(uint4*)((char*)As[P] + _r * 128 + ((ag ^ (_r & 7)) << 4)) = va[_j];       \
  }
// load 16 rows x 2KB: per instr, 512B CONTIGUOUS per row (DRAM-sequential)
#define LOAD_Bb(VB, NBASE)                                                      \
  _Pragma("unroll") for (int _j = 0; _j < 4; ++_j)                              \
    VB[_j] = *(const float4*)(tf + ((NBASE) + brow) * D_ + _j * 128 + bc * 4);
#define STORE_Bb(VB, P, BT)                                                     \
  {                                                                             \
    const int _row = (BT) * 16 + brow;                                          \
    float _ss = 0.f;                                                            \
    _Pragma("unroll") for (int _j = 0; _j < 4; ++_j) {                          \
      const float4 _f = VB[_j];                                                 \
      _ss += _f.x*_f.x + _f.y*_f.y + _f.z*_f.z + _f.w*_f.w;                     \
    }                                                                           \
    _ss += __shfl_xor(_ss, 1);  _ss += __shfl_xor(_ss, 2);                      \
    _ss += __shfl_xor(_ss, 4);  _ss += __shfl_xor(_ss, 8);                      \
    _ss += __shfl_xor(_ss, 16);                                                 \
    if ((lane & 31) == 0) rnS[P][_row] = 1.0f / sqrtf(_ss);                     \
    _Pragma("unroll") for (int _j = 0; _j < 4; ++_j) {                          \
      const float4 _f = VB[_j];                                                 \
      uint2 _o; _o.x = pk_bf16(_f.x, _f.y); _o.y = pk_bf16(_f.z, _f.w);         \
      const int _go = (bc >> 1) + _j * 16;                                      \
      *(uint2*)((char*)Bs[P] + _row * 1024 + ((_go ^ (_row & 7)) << 4)          \
                + (bc & 1) * 8) = _o;                                           \
    }                                                                           \
  }

  int task = blockIdx.x;                 // < 256 -> layer 0
  int lay  = task / NG_;
  int gl   = task % NG_;
  const u16* qbL = qb + (size_t)lay * B_ * D_;
  size_t nbase = (size_t)lay * N_ + (size_t)gl * 32;

  // prologue: stage A(0), B(group) fully (exposed waits, once per block)
  LOAD_A(qbL, 0);
  STORE_A(0);
  LOAD_Bb(vb0, nbase);
  LOAD_Bb(vb1, nbase + 16);
  STORE_Bb(vb0, 0, 0);
  STORE_Bb(vb1, 0, 1);
  int pb = 0;
  BAR_LG();

  for (; task < GTOT_; task += 256) {
    lay = task / NG_;
    gl  = task % NG_;
    qbL = qb + (size_t)lay * B_ * D_;
    const int n0 = gl * 32;
    const int taskn = task + 256;
    const bool hn = (taskn < GTOT_);
    const int layn = hn ? (taskn / NG_) : lay;
    const int gln  = hn ? (taskn % NG_) : 0;
    const u16* qbN = qb + (size_t)layn * B_ * D_;
    const size_t nbn = (size_t)layn * N_ + (size_t)gln * 32;

#pragma unroll
    for (int kt = 0; kt < 8; ++kt) {
      // issue loads (A first: its store-wait then leaves newer B loads in flight)
      if (kt < 7)       { LOAD_A(qbL, kt + 1); }
      else if (hn)      { LOAD_A(qbN, 0); }
      if (kt == 1 && hn) { LOAD_Bb(vb0, nbn); }
      if (kt == 3 && hn) { LOAD_Bb(vb1, nbn + 16); }
      SCHED_PIN();
      // MFMA phase: 8 MFMAs/wave
      const char* BsC = (const char*)Bs[pb];
      const char* AsC = (const char*)As[kt & 1];
#pragma unroll
      for (int ks = 0; ks < 2; ++ks) {
        const int gB = kt * 8 + ks * 4 + kg;
        const int rb = wn * 16 + rl;
        const short8 bfr = *(const short8*)(BsC + rb * 1024 + ((gB ^ (rb & 7)) << 4));
        const int gA = ks * 4 + kg;
#pragma unroll
        for (int mf = 0; mf < 4; ++mf) {
          const int m = wm * 64 + mf * 16 + rl;
          const short8 a = *(const short8*)(AsC + m * 128 + ((gA ^ (m & 7)) << 4));
          acc[mf] = __builtin_amdgcn_mfma_f32_16x16x32_bf16(a, bfr, acc[mf], 0, 0, 0);
        }
      }
      SCHED_PIN();
      // stores (reg-dep waits hit the oldest outstanding set -> precise)
      if (kt == 3 && hn) { STORE_Bb(vb0, pb ^ 1, 0); }
      if (kt == 5 && hn) { STORE_Bb(vb1, pb ^ 1, 1); }
      if (kt < 7 || hn)  { STORE_A((kt + 1) & 1); }
      BAR_LG();
    }

    // epilogue: threshold + deterministic slot append (cell = (q, group))
    {
      uint2* slotQ = slots + (size_t)lay * B_ * NG_ * SLOTS_;
      const int ncol = wn * 16 + rl;
      const int n = n0 + ncol;
      const float rn = rnS[pb][ncol];
      const int crow = (lane >> 4) * 4;
#pragma unroll
      for (int mf = 0; mf < 4; ++mf) {
#pragma unroll
        for (int j = 0; j < 4; ++j) {
          const float s = acc[mf][j] * rn;
          const int q = wm * 64 + mf * 16 + crow + j;
          if (s >= tauS[q]) {
            const int pos = atomicAdd(&lcnt[q], 1);
            if (pos < SLOTS_) {
              slotQ[((size_t)q * NG_ + gl) * SLOTS_ + pos] =
                  make_uint2(__float_as_uint(s), (unsigned)n);
            } else {                                   // rare (~400 total)
              const unsigned op = atomicAdd(ovfCnt, 1u);
              if (op < OVF_CAP)
                ovf[op] = make_uint2(__float_as_uint(s),
                                     ((unsigned)lay << 25) | ((unsigned)q << 17) | (unsigned)n);
            }
          }
          acc[mf][j] = 0.f;
        }
      }
    }
    BAR_LG();
    if (tid < B_) {
      lcnt[tid] = 0;
      if (hn && layn != lay) tauS[tid] = qn[layn * B_ + tid] * TAUC_;
    }
    pb ^= 1;
    BAR_LG();
  }
}

// ---- per-(layer,query): gather candidates -> rank-75 -> fp64 rescore -> exact rank ----
__global__ __launch_bounds__(256) void k_select(const uint2* __restrict__ slots,
                                                const uint2* __restrict__ ovf,
                                                const unsigned* __restrict__ ovfCnt,
                                                const float* __restrict__ tf,
                                                const float* __restrict__ qf,
                                                const int* __restrict__ labels,
                                                int* __restrict__ counts) {
  __shared__ float  sVal[CAP_];
  __shared__ int    sIdx[CAP_];
  __shared__ int    rIdxN[RCAP_];
  __shared__ double rVal[RCAP_];
  __shared__ unsigned s75u;
  __shared__ int nC, nRs;
  const int tid   = threadIdx.x;
  const int lane  = tid & 63;
  const int b     = blockIdx.x;
  const int layer = blockIdx.y;
  if (tid == 0) { nC = 0; nRs = 0; s75u = 0u; }
  __syncthreads();

  // gather from this query's contiguous slot strip (wave-ballot aggregated append)
  const uint2* sl = slots + ((size_t)layer * B_ + b) * NG_ * SLOTS_;
  const int nSlots = NG_ * SLOTS_;                  // 6250
  const int iters = (nSlots + 255) / 256;
  for (int it = 0; it < iters; ++it) {
    const int i = it * 256 + tid;
    float v = 0.f; unsigned nn = 0;
    if (i < nSlots) { uint2 e = sl[i]; v = __uint_as_float(e.x); nn = e.y; }
    const bool pred = (v > 0.f);
    const unsigned long long mk = __ballot(pred);
    if (mk) {
      int base = 0;
      if (lane == 0) base = atomicAdd(&nC, __popcll(mk));
      base = __shfl(base, 0);
      if (pred) {
        const int p = base + __popcll(mk & ((1ull << lane) - 1ull));
        if (p < CAP_) { sVal[p] = v; sIdx[p] = (int)nn; }
      }
    }
  }
  // overflow list (small, shared by all blocks)
  const int oc = min((int)*ovfCnt, OVF_CAP);
  for (int i = tid; i < oc; i += 256) {
    uint2 e = ovf[i];
    if ((int)(e.y >> 25) == layer && (int)((e.y >> 17) & 0xFFu) == b) {
      const int p = atomicAdd(&nC, 1);
      if (p < CAP_) { sVal[p] = __uint_as_float(e.x); sIdx[p] = (int)(e.y & 0x1FFFFu); }
    }
  }
  __syncthreads();
  const int m = min(nC, CAP_);

  // exact 75th-largest approx score (total order: value desc, idx asc)
  if (m > K_) {
    for (int c = tid; c < m; c += 256) {
      const float vc = sVal[c];
      const int   ic = sIdx[c];
      int r = 0;
      for (int j = 0; j < m; ++j) {
        const float vj = sVal[j];
        r += (vj > vc) || (vj == vc && sIdx[j] < ic);
      }
      if (r == K_ - 1) s75u = __float_as_uint(vc);   // unique writer
    }
  }
  __syncthreads();
  const float tr = (m > K_) ? (__uint_as_float(s75u) - MARGIN) : -1e30f;
  for (int c = tid; c < m; c += 256) {
    if (sVal[c] >= tr) {
      const int p = atomicAdd(&nRs, 1);
      if (p < RCAP_) rIdxN[p] = sIdx[c];
    }
  }
  __syncthreads();
  const int R = min(nRs, RCAP_);

  // exact fp64 rescore: one wave per candidate row
  const int wave = tid >> 6;
  const float* q     = qf + ((size_t)layer * B_ + b) * D_;
  const float* tbase = tf + (size_t)layer * N_ * D_;
  const float4 qa = *(const float4*)(q + lane * 8);
  const float4 qc = *(const float4*)(q + lane * 8 + 4);
  for (int c = wave; c < R; c += 4) {
    const float* t = tbase + (size_t)rIdxN[c] * D_ + lane * 8;
    const float4 ta = *(const float4*)t;
    const float4 tc = *(const float4*)(t + 4);
    double dot = (double)qa.x * ta.x + (double)qa.y * ta.y
               + (double)qa.z * ta.z + (double)qa.w * ta.w
               + (double)qc.x * tc.x + (double)qc.y * tc.y
               + (double)qc.z * tc.z + (double)qc.w * tc.w;
    double sq  = (double)ta.x * ta.x + (double)ta.y * ta.y
               + (double)ta.z * ta.z + (double)ta.w * ta.w
               + (double)tc.x * tc.x + (double)tc.y * tc.y
               + (double)tc.z * tc.z + (double)tc.w * tc.w;
#pragma unroll
    for (int off = 32; off; off >>= 1) {
      dot += __shfl_xor(dot, off);
      sq  += __shfl_xor(sq, off);
    }
    if (lane == 0) rVal[c] = dot / sqrt(sq);
  }
  __syncthreads();

  // exact rank among rescored set (contains all true top-75)
  for (int c = tid; c < R; c += 256) {
    const double vc = rVal[c];
    const int    ic = rIdxN[c];
    int r = 0;
    for (int j = 0; j < R; ++j) {
      const double vj = rVal[j];
      r += (vj > vc) || (vj == vc && rIdxN[j] < ic);
    }
    if (r < K_) atomicAdd(&counts[b * C_ + labels[ic]], 1);
  }
}

// ---- conformal p-values + credibility ----
__global__ __launch_bounds__(1024) void k_final(const int* __restrict__ counts,
                                                const int* __restrict__ cali,
                                                float* __restrict__ out) {
  __shared__ int   cal[NCALI_];
  __shared__ float pv[B_ * C_];
  const int tid = threadIdx.x;
  for (int i = tid; i < NCALI_; i += 1024) cal[i] = cali[i];
  __syncthreads();
  for (int t = tid; t < B_ * C_; t += 1024) {
    const int val = L_ * K_ - counts[t];
    int cntv = 0;
    for (int i = 0; i < NCALI_; ++i) cntv += (cal[i] >= val) ? 1 : 0;
    pv[t] = (float)cntv / (float)NCALI_;
  }
  __syncthreads();
  for (int b = tid; b < B_; b += 1024) {
    float best = pv[b * C_];
    int bc = 0;
#pragma unroll
    for (int c = 1; c < C_; ++c) {
      const float p = pv[b * C_ + c];
      if (p > best) { best = p; bc = c; }
    }
#pragma unroll
    for (int c = 0; c < C_; ++c) out[b * C_ + c] = (c == bc) ? best : 0.f;
  }
}

extern "C" void kernel_launch(void* const* d_in, const int* in_sizes, int n_in,
                              void* d_out, int out_size, void* d_ws, size_t ws_size,
                              hipStream_t stream) {
  (void)in_sizes; (void)n_in; (void)out_size;
  const float* train  = (const float*)d_in[0];
  const float* query  = (const float*)d_in[1];
  const int*   labels = (const int*)d_in[2];
  const int*   cali   = (const int*)d_in[3];
  float* out = (float*)d_out;

  char* ws = (char*)d_ws;
  u16*      qb     = (u16*)     (ws);            //    524,288 B [L*B*D bf16 linear]
  float*    qn     = (float*)   (ws + 524288);   //      2,048 B [L*B]
  int*      counts = (int*)     (ws + 526336);   //     10,240 B [B*C]
  unsigned* ovfCnt = (unsigned*)(ws + 536576);   //        256 B
  uint2*    ovf    = (uint2*)   (ws + 536832);   //    524,288 B [OVF_CAP]
  uint2*    slots  = (uint2*)   (ws + 1061120);  // 25,600,000 B [L*B*NG_*SLOTS_]
  if (ws_size < 26669312u) return;

  const long slot16 = 25600000 / 16;
  k_zero<<<dim3(2048), dim3(256), 0, stream>>>((uint4*)slots, slot16, ovfCnt);
  k_qprep<<<dim3(L_ * B_), dim3(64), 0, stream>>>(query, qb, qn, counts);
  k_gemm<<<dim3(256), dim3(512), 0, stream>>>(train, qb, qn, slots, ovf, ovfCnt);
  k_select<<<dim3(B_, L_), dim3(256), 0, stream>>>(slots, ovf, ovfCnt, train, query, labels, counts);
  k_final<<<dim3(1), dim3(1024), 0, stream>>>(counts, cali, out);
}

// Round 17
// 260.796 us; speedup vs baseline: 2.4273x; 2.4273x over previous
//
#include <hip/hip_runtime.h>
#include <hip/hip_bf16.h>
#include <stdint.h>

#define L_ 2
#define N_ 100000
#define D_ 512
#define B_ 256
#define C_ 10
#define K_ 75
#define NCALI_ 750
#define CAP_ 2048       // per-row candidate capacity in k_select (expect ~350 at z>2.7)
#define RCAP_ 1024      // rescore-set capacity (expect ~95)
#define TAUZ 2.7f       // pre-threshold in z units (true 75th at z~3.17, min ~3.0)
#define MARGIN 0.06f    // >> 5-sigma bf16 dot error (~0.008)
#define BN_ 64
#define NBX_ 1563       // (N_+63)/64
#define SLOTS_ 4        // slots per (query, block) cell
#define OVF_CAP 65536

typedef unsigned short u16;
typedef __attribute__((ext_vector_type(8))) short short8;
typedef __attribute__((ext_vector_type(4))) float f32x4;

// pack two floats into two rounded bf16s (lo in low 16 bits)
__device__ __forceinline__ unsigned pk_bf16(float lo, float hi) {
  unsigned a = __float_as_uint(lo) + 0x8000u;
  unsigned b = __float_as_uint(hi) + 0x8000u;
  return (a >> 16) | (b & 0xffff0000u);
}

// ---- zero the slot slab + overflow counter (every call: replay determinism) ----
__global__ __launch_bounds__(256) void k_zero(uint4* __restrict__ p, long n16,
                                              unsigned* __restrict__ ovfCnt) {
  long i = (long)blockIdx.x * 256 + threadIdx.x;
  const long stride = (long)gridDim.x * 256;
  const uint4 z = {0u, 0u, 0u, 0u};
  for (; i < n16; i += stride) p[i] = z;
  if (blockIdx.x == 0 && threadIdx.x == 0) *ovfCnt = 0u;
}

// ---- query -> bf16 (linear), query norms, zero class counts ----
__global__ __launch_bounds__(64) void k_qprep(const float* __restrict__ qf,
                                              u16* __restrict__ qb,
                                              float* __restrict__ qn,
                                              int* __restrict__ counts) {
  const int row  = blockIdx.x;      // 0..511 (l*256+b)
  const int lane = threadIdx.x;     // 0..63
  const float* src = qf + (size_t)row * D_ + lane * 8;
  float4 a = *(const float4*)(src);
  float4 b = *(const float4*)(src + 4);
  uint4 o;
  o.x = pk_bf16(a.x, a.y); o.y = pk_bf16(a.z, a.w);
  o.z = pk_bf16(b.x, b.y); o.w = pk_bf16(b.z, b.w);
  *(uint4*)(qb + (size_t)row * D_ + lane * 8) = o;
  float ss = a.x*a.x + a.y*a.y + a.z*a.z + a.w*a.w
           + b.x*b.x + b.y*b.y + b.z*b.z + b.w*b.w;
#pragma unroll
  for (int off = 32; off; off >>= 1) ss += __shfl_xor(ss, off);
  if (lane == 0) qn[row] = sqrtf(ss);
  if (row == 0)
    for (int i = lane; i < B_ * C_; i += 64) counts[i] = 0;
}

// ---- fused GEMM (round-5 proven structure, verbatim): simple 2-sync loop,
// BM=256, BN=64, BK=64; 4 waves; 256 threads; reg-staged both operands; train read once.
// Relies on 3-blocks/CU inter-block overlap (m114) rather than intra-block pipelining.
__global__ __launch_bounds__(256) void k_gemm(const float* __restrict__ tf,
                                              const u16* __restrict__ qb,
                                              const float* __restrict__ qn,
                                              uint2* __restrict__ slots,
                                              uint2* __restrict__ ovf,
                                              unsigned* __restrict__ ovfCnt) {
  __shared__ __align__(16) u16 As[256 * 64];   // 32 KB, XOR-swizzled
  __shared__ __align__(16) u16 Bs[BN_ * 64];   //  8 KB, XOR-swizzled
  __shared__ float rnS[BN_];
  __shared__ float tauS[B_];
  __shared__ int   lcnt[B_];                   // per-query block-local slot counter
  const int tid   = threadIdx.x;               // 0..255
  const int layer = blockIdx.y;
  const int bx    = blockIdx.x;
  const int n0    = bx * BN_;
  const int lane  = tid & 63, wave = tid >> 6; // 4 waves
  const int wr    = wave >> 1, wc = wave & 1;  // 2 M-halves x 2 N-halves
  const int kg    = lane >> 4, rl = lane & 15;

  const u16*   qbase = qb + (size_t)layer * B_ * D_;
  const float* tbase = tf + (size_t)layer * N_ * D_;

  tauS[tid] = qn[layer * B_ + tid] * (TAUZ / 22.627416997969522f);
  lcnt[tid] = 0;

  // A staging: 8 chunks/thread; chunk j -> row = j*32 + (tid>>3), c16 = tid&7
  const int arow0 = tid >> 3, ac16 = tid & 7;
  // B staging: 4 chunks/thread; chunk j -> row = j*16 + (tid>>4), c16 = tid&15
  const int brow0 = tid >> 4, bc16 = tid & 15;

  float ssj[4] = {0.f, 0.f, 0.f, 0.f};
  f32x4 acc[8][2];
  const f32x4 vz = {0.f, 0.f, 0.f, 0.f};
#pragma unroll
  for (int i = 0; i < 8; ++i) { acc[i][0] = vz; acc[i][1] = vz; }

  for (int kt = 0; kt < 8; ++kt) {
    // B global loads (fp32), coalesced: 4 rows x 256B contiguous per wave-instr
    float4 bf[4];
#pragma unroll
    for (int j = 0; j < 4; ++j) {
      int row = j * 16 + brow0;
      int n = n0 + row; n = n < N_ ? n : N_ - 1;
      bf[j] = *(const float4*)(tbase + (size_t)n * D_ + kt * 64 + bc16 * 4);
    }
    __syncthreads();   // previous tile fully consumed
    // A stage: 8 rows x 128B contiguous per wave-instr; swizzled ds_write_b128
#pragma unroll
    for (int j = 0; j < 8; ++j) {
      const int row = j * 32 + arow0;
      uint4 v = *(const uint4*)(qbase + (size_t)row * D_ + kt * 64 + ac16 * 8);
      *(uint4*)((char*)As + row * 128 + ((ac16 ^ (row & 7)) << 4)) = v;
    }
    // B stage: convert + swizzled ds_write_b64, accumulate ||t||^2 per chunk-row
#pragma unroll
    for (int j = 0; j < 4; ++j) {
      const int row = j * 16 + brow0;
      const float4 f = bf[j];
      ssj[j] += f.x*f.x + f.y*f.y + f.z*f.z + f.w*f.w;
      uint2 o;
      o.x = pk_bf16(f.x, f.y);
      o.y = pk_bf16(f.z, f.w);
      *(uint2*)((char*)Bs + row * 128 + ((((bc16 >> 1)) ^ (row & 7)) << 4) + (bc16 & 1) * 8) = o;
    }
    __syncthreads();   // tile ready
#pragma unroll
    for (int ks = 0; ks < 2; ++ks) {
      const int g = ks * 4 + kg;               // 8-elem k-granule index
      short8 bfr[2];
#pragma unroll
      for (int nf = 0; nf < 2; ++nf) {
        const int r = wc * 32 + nf * 16 + rl;
        bfr[nf] = *(const short8*)((const char*)Bs + r * 128 + ((g ^ (r & 7)) << 4));
      }
#pragma unroll
      for (int mf = 0; mf < 8; ++mf) {
        const int m = wr * 128 + mf * 16 + rl;
        const short8 a = *(const short8*)((const char*)As + m * 128 + ((g ^ (m & 7)) << 4));
        acc[mf][0] = __builtin_amdgcn_mfma_f32_16x16x32_bf16(a, bfr[0], acc[mf][0], 0, 0, 0);
        acc[mf][1] = __builtin_amdgcn_mfma_f32_16x16x32_bf16(a, bfr[1], acc[mf][1], 0, 0, 0);
      }
    }
  }
  // full-row 1/||t||: reduce ssj within 16-lane chunk groups
#pragma unroll
  for (int j = 0; j < 4; ++j) {
    float s = ssj[j];
    s += __shfl_xor(s, 1);
    s += __shfl_xor(s, 2);
    s += __shfl_xor(s, 4);
    s += __shfl_xor(s, 8);
    if ((lane & 15) == 0) rnS[j * 16 + wave * 4 + (lane >> 4)] = 1.0f / sqrtf(s);
  }
  __syncthreads();

  // epilogue: deterministic slot append, NO contended global atomics
  const int crow = (lane >> 4) * 4;
  uint2* slotL = slots + (size_t)layer * B_ * NBX_ * SLOTS_;
#pragma unroll
  for (int nf = 0; nf < 2; ++nf) {
    const int cidx = wc * 32 + nf * 16 + rl;
    const int n = n0 + cidx;
    if (n < N_) {
      const float rn = rnS[cidx];
#pragma unroll
      for (int mf = 0; mf < 8; ++mf) {
        const int bq0 = wr * 128 + mf * 16 + crow;
#pragma unroll
        for (int j = 0; j < 4; ++j) {
          const float s = acc[mf][nf][j] * rn;
          const int bq = bq0 + j;
          if (s >= tauS[bq]) {
            const int pos = atomicAdd(&lcnt[bq], 1);   // LDS atomic: cheap
            if (pos < SLOTS_) {
              slotL[((size_t)bq * NBX_ + bx) * SLOTS_ + pos] =
                  make_uint2(__float_as_uint(s), (unsigned)n);
            } else {                                    // rare (~3 total at z>2.7)
              const unsigned op = atomicAdd(ovfCnt, 1u);
              if (op < OVF_CAP)
                ovf[op] = make_uint2(__float_as_uint(s),
                                     ((unsigned)layer << 25) | ((unsigned)bq << 17) | (unsigned)n);
            }
          }
        }
      }
    }
  }
}

// ---- per-(layer,query): gather candidates -> rank-75 -> fp64 rescore -> exact rank ----
__global__ __launch_bounds__(256) void k_select(const uint2* __restrict__ slots,
                                                const uint2* __restrict__ ovf,
                                                const unsigned* __restrict__ ovfCnt,
                                                const float* __restrict__ tf,
                                                const float* __restrict__ qf,
                                                const int* __restrict__ labels,
                                                int* __restrict__ counts) {
  __shared__ float  sVal[CAP_];
  __shared__ int    sIdx[CAP_];
  __shared__ int    rIdxN[RCAP_];
  __shared__ double rVal[RCAP_];
  __shared__ unsigned s75u;
  __shared__ int nC, nRs;
  const int tid   = threadIdx.x;
  const int lane  = tid & 63;
  const int b     = blockIdx.x;
  const int layer = blockIdx.y;
  if (tid == 0) { nC = 0; nRs = 0; s75u = 0u; }
  __syncthreads();

  // gather from this query's contiguous slot strip (wave-ballot aggregated append)
  const uint2* sl = slots + ((size_t)layer * B_ + b) * NBX_ * SLOTS_;
  const int nSlots = NBX_ * SLOTS_;                 // 6252
  const int iters = (nSlots + 255) / 256;
  for (int it = 0; it < iters; ++it) {
    const int i = it * 256 + tid;
    float v = 0.f; unsigned nn = 0;
    if (i < nSlots) { uint2 e = sl[i]; v = __uint_as_float(e.x); nn = e.y; }
    const bool pred = (v > 0.f);
    const unsigned long long mk = __ballot(pred);
    if (mk) {
      int base = 0;
      if (lane == 0) base = atomicAdd(&nC, __popcll(mk));
      base = __shfl(base, 0);
      if (pred) {
        const int p = base + __popcll(mk & ((1ull << lane) - 1ull));
        if (p < CAP_) { sVal[p] = v; sIdx[p] = (int)nn; }
      }
    }
  }
  // overflow list (tiny, shared by all blocks)
  const int oc = min((int)*ovfCnt, OVF_CAP);
  for (int i = tid; i < oc; i += 256) {
    uint2 e = ovf[i];
    if ((int)(e.y >> 25) == layer && (int)((e.y >> 17) & 0xFFu) == b) {
      const int p = atomicAdd(&nC, 1);
      if (p < CAP_) { sVal[p] = __uint_as_float(e.x); sIdx[p] = (int)(e.y & 0x1FFFFu); }
    }
  }
  __syncthreads();
  const int m = min(nC, CAP_);

  // exact 75th-largest approx score (total order: value desc, idx asc)
  if (m > K_) {
    for (int c = tid; c < m; c += 256) {
      const float vc = sVal[c];
      const int   ic = sIdx[c];
      int r = 0;
      for (int j = 0; j < m; ++j) {
        const float vj = sVal[j];
        r += (vj > vc) || (vj == vc && sIdx[j] < ic);
      }
      if (r == K_ - 1) s75u = __float_as_uint(vc);   // unique writer
    }
  }
  __syncthreads();
  const float tr = (m > K_) ? (__uint_as_float(s75u) - MARGIN) : -1e30f;
  for (int c = tid; c < m; c += 256) {
    if (sVal[c] >= tr) {
      const int p = atomicAdd(&nRs, 1);
      if (p < RCAP_) rIdxN[p] = sIdx[c];
    }
  }
  __syncthreads();
  const int R = min(nRs, RCAP_);

  // exact fp64 rescore: one wave per candidate row
  const int wave = tid >> 6;
  const float* q     = qf + ((size_t)layer * B_ + b) * D_;
  const float* tbase = tf + (size_t)layer * N_ * D_;
  const float4 qa = *(const float4*)(q + lane * 8);
  const float4 qc = *(const float4*)(q + lane * 8 + 4);
  for (int c = wave; c < R; c += 4) {
    const float* t = tbase + (size_t)rIdxN[c] * D_ + lane * 8;
    const float4 ta = *(const float4*)t;
    const float4 tc = *(const float4*)(t + 4);
    double dot = (double)qa.x * ta.x + (double)qa.y * ta.y
               + (double)qa.z * ta.z + (double)qa.w * ta.w
               + (double)qc.x * tc.x + (double)qc.y * tc.y
               + (double)qc.z * tc.z + (double)qc.w * tc.w;
    double sq  = (double)ta.x * ta.x + (double)ta.y * ta.y
               + (double)ta.z * ta.z + (double)ta.w * ta.w
               + (double)tc.x * tc.x + (double)tc.y * tc.y
               + (double)tc.z * tc.z + (double)tc.w * tc.w;
#pragma unroll
    for (int off = 32; off; off >>= 1) {
      dot += __shfl_xor(dot, off);
      sq  += __shfl_xor(sq, off);
    }
    if (lane == 0) rVal[c] = dot / sqrt(sq);
  }
  __syncthreads();

  // exact rank among rescored set (contains all true top-75)
  for (int c = tid; c < R; c += 256) {
    const double vc = rVal[c];
    const int    ic = rIdxN[c];
    int r = 0;
    for (int j = 0; j < R; ++j) {
      const double vj = rVal[j];
      r += (vj > vc) || (vj == vc && rIdxN[j] < ic);
    }
    if (r < K_) atomicAdd(&counts[b * C_ + labels[ic]], 1);
  }
}

// ---- conformal p-values + credibility ----
__global__ __launch_bounds__(1024) void k_final(const int* __restrict__ counts,
                                                const int* __restrict__ cali,
                                                float* __restrict__ out) {
  __shared__ int   cal[NCALI_];
  __shared__ float pv[B_ * C_];
  const int tid = threadIdx.x;
  for (int i = tid; i < NCALI_; i += 1024) cal[i] = cali[i];
  __syncthreads();
  for (int t = tid; t < B_ * C_; t += 1024) {
    const int val = L_ * K_ - counts[t];
    int cntv = 0;
    for (int i = 0; i < NCALI_; ++i) cntv += (cal[i] >= val) ? 1 : 0;
    pv[t] = (float)cntv / (float)NCALI_;
  }
  __syncthreads();
  for (int b = tid; b < B_; b += 1024) {
    float best = pv[b * C_];
    int bc = 0;
#pragma unroll
    for (int c = 1; c < C_; ++c) {
      const float p = pv[b * C_ + c];
      if (p > best) { best = p; bc = c; }
    }
#pragma unroll
    for (int c = 0; c < C_; ++c) out[b * C_ + c] = (c == bc) ? best : 0.f;
  }
}

extern "C" void kernel_launch(void* const* d_in, const int* in_sizes, int n_in,
                              void* d_out, int out_size, void* d_ws, size_t ws_size,
                              hipStream_t stream) {
  (void)in_sizes; (void)n_in; (void)out_size;
  const float* train  = (const float*)d_in[0];
  const float* query  = (const float*)d_in[1];
  const int*   labels = (const int*)d_in[2];
  const int*   cali   = (const int*)d_in[3];
  float* out = (float*)d_out;

  char* ws = (char*)d_ws;
  u16*      qb     = (u16*)     (ws);            //    524,288 B [L*B*D bf16 linear]
  float*    qn     = (float*)   (ws + 524288);   //      2,048 B [L*B]
  int*      counts = (int*)     (ws + 526336);   //     10,240 B [B*C]
  unsigned* ovfCnt = (unsigned*)(ws + 536576);   //        256 B
  uint2*    ovf    = (uint2*)   (ws + 536832);   //    524,288 B [OVF_CAP]
  uint2*    slots  = (uint2*)   (ws + 1061120);  // 25,608,192 B [L*B*NBX_*SLOTS_]
  if (ws_size < 26669312u) return;

  const long slot16 = 25608192 / 16;
  k_zero<<<dim3(2048), dim3(256), 0, stream>>>((uint4*)slots, slot16, ovfCnt);
  k_qprep<<<dim3(L_ * B_), dim3(64), 0, stream>>>(query, qb, qn, counts);
  k_gemm<<<dim3(NBX_, L_), dim3(256), 0, stream>>>(train, qb, qn, slots, ovf, ovfCnt);
  k_select<<<dim3(B_, L_), dim3(256), 0, stream>>>(slots, ovf, ovfCnt, train, query, labels, counts);
  k_final<<<dim3(1), dim3(1024), 0, stream>>>(counts, cali, out);
}